// Round 16
// baseline (234.261 us; speedup 1.0000x reference)
//
#include <hip/hip_runtime.h>
#include <hip/hip_bf16.h>
#include <limits.h>

#define N_NODES 50000
#define N_EDGES 800000
#define HID 128
#define N_LAYER 3
#define FC_HID 256
#define N_CLASS 10
#define N_GRAPHS 64
#define NBKT 98                          // raw dst>>9; raw dst < 50000 -> buckets 0..97
#define BIN_NB 256                       // edge-slice blocks (k_minh / k_bin must match)
#define PER_BLK ((N_EDGES + BIN_NB - 1) / BIN_NB)  // 3125

typedef __attribute__((ext_vector_type(8))) short short8;   // 8 bf16 = 4 VGPRs
typedef __attribute__((ext_vector_type(4))) float f32x4;

__device__ inline unsigned f2bf(float f) {  // RNE f32 -> bf16 bits
    unsigned u = __float_as_uint(f);
    return (u + 0x7FFFu + ((u >> 16) & 1u)) >> 16;
}

// ---- fused: edge min + bucket hist + x->bf16 cvt + W bf16 transpose prep + pooled zero ----
// 256 blocks x 512 threads. cvt/wprep/zero are independent payloads overlapping the edge scan.
__global__ __launch_bounds__(512) void k_minh(
    const int* __restrict__ ei, const float* __restrict__ x,
    const float* __restrict__ Wl, const float* __restrict__ Wr,
    int* __restrict__ bmin, int* __restrict__ hist, unsigned* __restrict__ xb,
    unsigned* __restrict__ wlh, unsigned* __restrict__ wrh,
    float* __restrict__ pooled) {
    __shared__ int red[512];
    __shared__ int lh[NBKT];
    const int b = blockIdx.x, t = threadIdx.x;
    if (t < NBKT) lh[t] = 0;
    __syncthreads();
    int gid = b * 512 + t;
    if (gid < N_GRAPHS * HID * N_LAYER) pooled[gid] = 0.f;  // zero pooled accumulator
    int e0 = b * PER_BLK, e1 = min(e0 + PER_BLK, N_EDGES);
    int v = INT_MAX;
    for (int j = e0 + t; j < e1; j += 512) {
        int s = ei[j], d = ei[N_EDGES + j];
        v = min(v, min(s, d));
        atomicAdd(&lh[d >> 9], 1);
    }
    // x -> bf16x2 packed (grid-stride over 1.6M float4 groups)
    for (int i = gid; i < N_NODES * HID / 4; i += BIN_NB * 512) {
        float4 xv = *(const float4*)(x + (size_t)i * 4);
        uint2 o;
        o.x = f2bf(xv.x) | (f2bf(xv.y) << 16);
        o.y = f2bf(xv.z) | (f2bf(xv.w) << 16);
        *(uint2*)(xb + (size_t)i * 2) = o;
    }
    if (b >= 250) {  // W prep: Wt[n][k] bf16; one matrix per block
        int w = b - 250;
        const float* src = (w < 3) ? (Wl + (size_t)w * HID * HID)
                                   : (Wr + (size_t)(w - 3) * HID * HID);
        unsigned* dh = (w < 3) ? (wlh + (size_t)w * HID * 64) : (wrh + (size_t)(w - 3) * HID * 64);
        for (int i = 0; i < 16; ++i) {
            int u = t * 16 + i;           // n = u>>6 (out col), kk = u&63 (k pair)
            int n = u >> 6, kk = u & 63;
            float v0 = src[(size_t)(2 * kk) * HID + n];
            float v1 = src[(size_t)(2 * kk + 1) * HID + n];
            dh[u] = f2bf(v0) | (f2bf(v1) << 16);
        }
    }
    red[t] = v;
    __syncthreads();
    for (int off = 256; off > 0; off >>= 1) {
        if (t < off) red[t] = min(red[t], red[t + off]);
        __syncthreads();
    }
    if (t == 0) bmin[b] = red[0];
    if (t < NBKT) hist[b * NBKT + t] = lh[t];
}

// ---- single-pass binning: edge -> bucket-contiguous packed ebuf ----
// emin + colex + bboff all derived locally from bmin/hist (kills the k_base stage).
__global__ __launch_bounds__(512) void k_bin(const int* __restrict__ ei,
                                             const int* __restrict__ bmin,
                                             const int* __restrict__ hist,
                                             unsigned* __restrict__ ebuf) {
    __shared__ int smin[256];
    __shared__ int sscan[128];
    __shared__ int lcnt[NBKT];
    __shared__ int lbase[NBKT];
    const int t = threadIdx.x, blk = blockIdx.x;
    if (t < 256) smin[t] = bmin[t];
    __syncthreads();
    for (int off = 128; off > 0; off >>= 1) {
        if (t < off) smin[t] = min(smin[t], smin[t + off]);
        __syncthreads();
    }
    // per-bucket: colex (prefix over slices < blk) and btot (all slices), coalesced row reads
    int tot = 0, cx = 0;
    if (t < NBKT) {
        for (int j = 0; j < BIN_NB; ++j) {
            int h = hist[j * NBKT + t];
            tot += h;
            cx += (j < blk) ? h : 0;
        }
    }
    if (t < 128) sscan[t] = tot;
    __syncthreads();
    for (int off = 1; off < 128; off <<= 1) {
        int u = (t >= off && t < 128) ? sscan[t - off] : 0;
        __syncthreads();
        if (t < 128) sscan[t] += u;
        __syncthreads();
    }
    if (t < NBKT) {
        lcnt[t] = 0;
        lbase[t] = (sscan[t] - tot) + cx;  // bboff[t] + colex[blk][t]
    }
    __syncthreads();
    int m = smin[0];
    int e0 = blk * PER_BLK, e1 = min(e0 + PER_BLK, N_EDGES);
    for (int j = e0 + t; j < e1; j += 512) {
        int s = ei[j] - m, d = ei[N_EDGES + j];
        int bk = d >> 9;
        int idx = atomicAdd(&lcnt[bk], 1);
        ebuf[lbase[bk] + idx] = ((unsigned)s << 9) | (unsigned)(d & 511);
    }
}

// ---- per-bucket: local deg/scan -> rp, invd, then CSR placement (bboff/emin local) ----
__global__ __launch_bounds__(512) void k_scatter2(const unsigned* __restrict__ ebuf,
                                                  const int* __restrict__ bmin,
                                                  const int* __restrict__ hist,
                                                  int* __restrict__ rp,
                                                  float* __restrict__ invd,
                                                  int* __restrict__ csr) {
    __shared__ int ldeg[512];
    __shared__ int lsc[512];
    __shared__ int lfill[512];
    __shared__ int bbsh[NBKT + 1];
    __shared__ int smin[256];
    const int b = blockIdx.x, t = threadIdx.x;
    if (t < 256) smin[t] = bmin[t];
    __syncthreads();
    for (int off = 128; off > 0; off >>= 1) {
        if (t < off) smin[t] = min(smin[t], smin[t + off]);
        __syncthreads();
    }
    int tot = 0;
    if (t < NBKT) {
        for (int j = 0; j < BIN_NB; ++j) tot += hist[j * NBKT + t];
    }
    if (t < 128) lsc[t] = tot;
    __syncthreads();
    for (int off = 1; off < 128; off <<= 1) {
        int u = (t >= off && t < 128) ? lsc[t - off] : 0;
        __syncthreads();
        if (t < 128) lsc[t] += u;
        __syncthreads();
    }
    if (t < NBKT) bbsh[t] = lsc[t] - tot;
    if (t == 127) bbsh[NBKT] = lsc[127];
    __syncthreads();
    int m = smin[0];
    if (b == NBKT) {  // tail: nodes past bucket coverage + rp[N_NODES]
        if (t == 0) rp[N_NODES] = bbsh[NBKT];
        for (int nd = NBKT * 512 - m + t; nd < N_NODES; nd += 512)
            if (nd >= 0) { rp[nd] = N_EDGES; invd[nd] = 1.0f; }
        return;
    }
    int beg = bbsh[b], end = bbsh[b + 1];
    ldeg[t] = 0;
    lfill[t] = 0;
    __syncthreads();
    for (int e = beg + t; e < end; e += 512)
        atomicAdd(&ldeg[ebuf[e] & 511], 1);
    __syncthreads();
    int dv = ldeg[t];
    lsc[t] = dv;
    __syncthreads();
    for (int off = 1; off < 512; off <<= 1) {
        int u = (t >= off) ? lsc[t - off] : 0;
        __syncthreads();
        lsc[t] += u;
        __syncthreads();
    }
    int base = beg + lsc[t] - dv;  // global CSR start for this node slot
    lsc[t] = base;
    int nd = (b << 9) + t - m;
    if (nd >= 0 && nd < N_NODES) {
        rp[nd] = base;
        invd[nd] = 1.0f / (float)max(dv, 1);
    }
    __syncthreads();
    for (int e = beg + t; e < end; e += 512) {
        unsigned p = ebuf[e];
        int loc = p & 511;
        int pos = lsc[loc] + atomicAdd(&lfill[loc], 1);
        csr[pos] = (int)(p >> 9);
    }
}

// ---------------- mean aggregation: one wave per node, full 256B rows, 16-deep MLP ----------
__global__ void k_agg(const unsigned* __restrict__ hb, const int* __restrict__ rp,
                      const int* __restrict__ csr, const float* __restrict__ invd,
                      unsigned* __restrict__ aggb) {
    const int n = blockIdx.x;
    const int lane = threadIdx.x;  // 64; lane covers features 2*lane, 2*lane+1
    int beg = rp[n], end = rp[n + 1];
    float a0 = 0, a1 = 0, b0 = 0, b1 = 0, c0 = 0, c1 = 0, d0 = 0, d1 = 0;
    int e = beg;
    for (; e + 16 <= end; e += 16) {  // 16 outstanding loads: one batch covers avg degree
        int s[16];
        unsigned u[16];
#pragma unroll
        for (int i = 0; i < 16; ++i) s[i] = csr[e + i];
#pragma unroll
        for (int i = 0; i < 16; ++i) u[i] = hb[(size_t)s[i] * 64 + lane];
#pragma unroll
        for (int i = 0; i < 16; i += 4) {
            a0 += __uint_as_float(u[i] << 16);     a1 += __uint_as_float(u[i] & 0xFFFF0000u);
            b0 += __uint_as_float(u[i + 1] << 16); b1 += __uint_as_float(u[i + 1] & 0xFFFF0000u);
            c0 += __uint_as_float(u[i + 2] << 16); c1 += __uint_as_float(u[i + 2] & 0xFFFF0000u);
            d0 += __uint_as_float(u[i + 3] << 16); d1 += __uint_as_float(u[i + 3] & 0xFFFF0000u);
        }
    }
    for (; e + 4 <= end; e += 4) {
        int s0 = csr[e], s1 = csr[e + 1], s2 = csr[e + 2], s3 = csr[e + 3];
        unsigned u0 = hb[(size_t)s0 * 64 + lane];
        unsigned u1 = hb[(size_t)s1 * 64 + lane];
        unsigned u2 = hb[(size_t)s2 * 64 + lane];
        unsigned u3 = hb[(size_t)s3 * 64 + lane];
        a0 += __uint_as_float(u0 << 16); a1 += __uint_as_float(u0 & 0xFFFF0000u);
        b0 += __uint_as_float(u1 << 16); b1 += __uint_as_float(u1 & 0xFFFF0000u);
        c0 += __uint_as_float(u2 << 16); c1 += __uint_as_float(u2 & 0xFFFF0000u);
        d0 += __uint_as_float(u3 << 16); d1 += __uint_as_float(u3 & 0xFFFF0000u);
    }
    for (; e < end; ++e) {
        unsigned u = hb[(size_t)csr[e] * 64 + lane];
        a0 += __uint_as_float(u << 16);
        a1 += __uint_as_float(u & 0xFFFF0000u);
    }
    float iv = invd[n];
    unsigned o = f2bf((a0 + b0 + c0 + d0) * iv) | (f2bf((a1 + b1 + c1 + d1) * iv) << 16);
    aggb[(size_t)n * 64 + lane] = o;
}

// ---------------- MFMA fused: h_out = relu(agg@Wl + hin@Wr + b); pooled += per-graph sums ----
// kc-loop software-pipelined: next-kc A/H fragments prefetched under current-kc MFMAs.
__global__ __launch_bounds__(256, 4) void k_gemm(
    const unsigned* __restrict__ aggb, const unsigned* __restrict__ hinb,
    const unsigned* __restrict__ wlh, const unsigned* __restrict__ wrh,
    const float* __restrict__ bias, const int* __restrict__ batch,
    unsigned* __restrict__ houtb, float* __restrict__ pooled, int layer, int store_h) {
    __shared__ float Ts[64 * 132];  // stride 132: epilogue writes <=2-way bank aliased
    __shared__ int bs[64];
    const int tx = threadIdx.x;
    const int wave = tx >> 6, lane = tx & 63;
    const int row0 = blockIdx.x * 64;
    const int lrow = lane & 15, kgrp = lane >> 4;

    if (tx < 64) {
        int grow = row0 + tx;
        bs[tx] = (grow < N_NODES) ? batch[grow] : -1;
    }

    f32x4 acc[4][2];
#pragma unroll
    for (int m = 0; m < 4; ++m)
#pragma unroll
        for (int n = 0; n < 2; ++n) acc[m][n] = (f32x4){0.f, 0.f, 0.f, 0.f};
    const short8 zf = {0, 0, 0, 0, 0, 0, 0, 0};

    short8 af[4], hf[4], afn[4], hfn[4];
    const int koff0 = kgrp * 4;
#pragma unroll
    for (int m = 0; m < 4; ++m) {  // prologue: load kc=0 fragments
        int r = row0 + m * 16 + lrow;
        if (r < N_NODES) {
            af[m] = *(const short8*)(aggb + (size_t)r * 64 + koff0);
            hf[m] = *(const short8*)(hinb + (size_t)r * 64 + koff0);
        } else {
            af[m] = zf;
            hf[m] = zf;
        }
    }
#pragma unroll
    for (int kc = 0; kc < 4; ++kc) {
        if (kc < 3) {  // prefetch kc+1 fragments; latency hides under this kc's MFMAs
            const int koffn = (kc + 1) * 16 + kgrp * 4;
#pragma unroll
            for (int m = 0; m < 4; ++m) {
                int r = row0 + m * 16 + lrow;
                if (r < N_NODES) {
                    afn[m] = *(const short8*)(aggb + (size_t)r * 64 + koffn);
                    hfn[m] = *(const short8*)(hinb + (size_t)r * 64 + koffn);
                } else {
                    afn[m] = zf;
                    hfn[m] = zf;
                }
            }
        }
        const int koff = kc * 16 + kgrp * 4;
#pragma unroll
        for (int n = 0; n < 2; ++n) {
            int wn = wave * 2 + n;  // col tile 0..7
            size_t wbase = (size_t)(wn * 16 + lrow) * 64 + koff;
            short8 fl = *(const short8*)(wlh + wbase);
            short8 fr = *(const short8*)(wrh + wbase);
#pragma unroll
            for (int m = 0; m < 4; ++m) {
                acc[m][n] = __builtin_amdgcn_mfma_f32_16x16x32_bf16(af[m], fl, acc[m][n], 0, 0, 0);
                acc[m][n] = __builtin_amdgcn_mfma_f32_16x16x32_bf16(hf[m], fr, acc[m][n], 0, 0, 0);
            }
        }
        if (kc < 3) {
#pragma unroll
            for (int m = 0; m < 4; ++m) { af[m] = afn[m]; hf[m] = hfn[m]; }
        }
    }

    // C/D layout: col = lane&15, row = (lane>>4)*4 + reg  [guide §3, m89-verified]
#pragma unroll
    for (int n = 0; n < 2; ++n) {
        int c = wave * 32 + n * 16 + lrow;
        float bb = bias[c];
#pragma unroll
        for (int m = 0; m < 4; ++m)
#pragma unroll
            for (int reg = 0; reg < 4; ++reg) {
                int r = m * 16 + kgrp * 4 + reg;
                Ts[r * 132 + c] = fmaxf(acc[m][n][reg] + bb, 0.f);
            }
    }
    __syncthreads();

    // bf16 h_out store (skipped for the last layer - no consumer)
    if (store_h) {
#pragma unroll
        for (int it = 0; it < 4; ++it) {
            int f = it * 256 + tx;
            int r = f >> 4, slot = f & 15;
            int grow = row0 + r;
            if (grow < N_NODES) {
                const float* ts = &Ts[r * 132 + slot * 8];
                uint4 o;
                o.x = f2bf(ts[0]) | (f2bf(ts[1]) << 16);
                o.y = f2bf(ts[2]) | (f2bf(ts[3]) << 16);
                o.z = f2bf(ts[4]) | (f2bf(ts[5]) << 16);
                o.w = f2bf(ts[6]) | (f2bf(ts[7]) << 16);
                *(uint4*)(houtb + (size_t)grow * 64 + slot * 4) = o;
            }
        }
    }

    // per-graph pooled pre-reduction: 256 threads = 128 cols x 2 row-halves (batch sorted)
    {
        int j = tx & 127, half = tx >> 7;
        int rbeg = half * 32, rend = rbeg + 32;
        float run = 0.f;
        int curb = bs[rbeg];
        for (int r = rbeg; r < rend; ++r) {
            int bb = bs[r];
            if (bb != curb) {
                if (curb >= 0)
                    atomicAdd(&pooled[(size_t)curb * (HID * N_LAYER) + layer * HID + j], run);
                run = 0.f;
                curb = bb;
            }
            run += Ts[r * 132 + j];
        }
        if (curb >= 0)
            atomicAdd(&pooled[(size_t)curb * (HID * N_LAYER) + layer * HID + j], run);
    }
}

// ---------------- FC head: one block per graph (counts via local binary search) ----------------
__global__ void k_fc(const float* __restrict__ pooled, const int* __restrict__ batch,
                     const float* __restrict__ fc1w, const float* __restrict__ fc1b,
                     const float* __restrict__ fc2w, const float* __restrict__ fc2b,
                     float* __restrict__ out) {
    __shared__ float pr[HID * N_LAYER];
    __shared__ float a1[FC_HID];
    __shared__ float invc_sh;
    const int g = blockIdx.x, t = threadIdx.x;  // 256 threads
    if (t == 0) {
        int lo = 0, hi = N_NODES;
        while (lo < hi) { int mid = (lo + hi) >> 1; if (batch[mid] < g) lo = mid + 1; else hi = mid; }
        int lb = lo;
        lo = lb; hi = N_NODES;
        while (lo < hi) { int mid = (lo + hi) >> 1; if (batch[mid] <= g) lo = mid + 1; else hi = mid; }
        invc_sh = 1.0f / fmaxf((float)(lo - lb), 1.0f);
    }
    __syncthreads();
    float invc = invc_sh;
    for (int i = t; i < HID * N_LAYER; i += FC_HID)
        pr[i] = pooled[(size_t)g * (HID * N_LAYER) + i] * invc;
    __syncthreads();
    float acc = fc1b[t];
    for (int k = 0; k < HID * N_LAYER; ++k)
        acc = fmaf(pr[k], fc1w[(size_t)k * FC_HID + t], acc);
    a1[t] = fmaxf(acc, 0.f);
    __syncthreads();
    if (t < N_CLASS) {
        float o = fc2b[t];
        for (int k = 0; k < FC_HID; ++k)
            o = fmaf(a1[k], fc2w[(size_t)k * N_CLASS + t], o);
        out[(size_t)g * N_CLASS + t] = o;
    }
}

extern "C" void kernel_launch(void* const* d_in, const int* in_sizes, int n_in,
                              void* d_out, int out_size, void* d_ws, size_t ws_size,
                              hipStream_t stream) {
    const float* x = (const float*)d_in[0];
    const int* ei = (const int*)d_in[1];
    const int* batch = (const int*)d_in[2];
    const float* Wl = (const float*)d_in[3];
    const float* Wr = (const float*)d_in[4];
    const float* bl = (const float*)d_in[5];
    const float* fc1w = (const float*)d_in[6];
    const float* fc1b = (const float*)d_in[7];
    const float* fc2w = (const float*)d_in[8];
    const float* fc2b = (const float*)d_in[9];
    float* out = (float*)d_out;

    char* ws = (char*)d_ws;
    size_t off = 0;
    auto alloc = [&](size_t bytes) {
        void* p = ws + off;
        off += (bytes + 255) & ~size_t(255);
        return p;
    };
    // all buffers fully written on-device every call -> no memsets needed
    int* bmin = (int*)alloc(BIN_NB * 4);
    float* pooled = (float*)alloc((size_t)N_GRAPHS * HID * N_LAYER * 4);  // zeroed by k_minh
    int* hist = (int*)alloc((size_t)BIN_NB * NBKT * 4);
    int* rp = (int*)alloc((N_NODES + 1) * 4);
    float* invd = (float*)alloc(N_NODES * 4);
    unsigned* ebuf = (unsigned*)alloc((size_t)N_EDGES * 4);
    int* csr = (int*)alloc((size_t)N_EDGES * 4);
    unsigned* wlh = (unsigned*)alloc((size_t)N_LAYER * HID * 64 * 4);
    unsigned* wrh = (unsigned*)alloc((size_t)N_LAYER * HID * 64 * 4);
    unsigned* aggb = (unsigned*)alloc((size_t)N_NODES * 64 * 4);   // bf16x2 packed
    unsigned* xb = (unsigned*)alloc((size_t)N_NODES * 64 * 4);
    unsigned* hb1 = (unsigned*)alloc((size_t)N_NODES * 64 * 4);
    unsigned* hb2 = (unsigned*)alloc((size_t)N_NODES * 64 * 4);

    k_minh<<<BIN_NB, 512, 0, stream>>>(ei, x, Wl, Wr, bmin, hist, xb, wlh, wrh, pooled);
    k_bin<<<BIN_NB, 512, 0, stream>>>(ei, bmin, hist, ebuf);
    k_scatter2<<<NBKT + 1, 512, 0, stream>>>(ebuf, bmin, hist, rp, invd, csr);

    const unsigned* hin = xb;
    unsigned* houts[3] = {hb1, hb2, hb1};
    for (int layer = 0; layer < N_LAYER; ++layer) {
        k_agg<<<N_NODES, 64, 0, stream>>>(hin, rp, csr, invd, aggb);
        k_gemm<<<(N_NODES + 63) / 64, 256, 0, stream>>>(
            aggb, hin,
            wlh + (size_t)layer * HID * 64, wrh + (size_t)layer * HID * 64,
            bl + (size_t)layer * HID, batch, houts[layer], pooled, layer,
            layer < N_LAYER - 1 ? 1 : 0);
        hin = houts[layer];
    }
    k_fc<<<N_GRAPHS, 256, 0, stream>>>(pooled, batch, fc1w, fc1b, fc2w, fc2b, out);
}

// Round 17
// 225.828 us; speedup vs baseline: 1.0373x; 1.0373x over previous
//
#include <hip/hip_runtime.h>
#include <hip/hip_bf16.h>
#include <limits.h>

#define N_NODES 50000
#define N_EDGES 800000
#define HID 128
#define N_LAYER 3
#define FC_HID 256
#define N_CLASS 10
#define N_GRAPHS 64
#define NBKT 98                          // raw dst>>9; raw dst < 50000 -> buckets 0..97
#define BIN_NB 256                       // edge-slice blocks (k_minh / k_bin must match)
#define PER_BLK ((N_EDGES + BIN_NB - 1) / BIN_NB)  // 3125

typedef __attribute__((ext_vector_type(8))) short short8;   // 8 bf16 = 4 VGPRs
typedef __attribute__((ext_vector_type(4))) float f32x4;

__device__ inline unsigned f2bf(float f) {  // RNE f32 -> bf16 bits
    unsigned u = __float_as_uint(f);
    return (u + 0x7FFFu + ((u >> 16) & 1u)) >> 16;
}

// ---- fused: edge min + bucket hist + x->bf16 cvt + W bf16 transpose prep ----
// 256 blocks x 512 threads. cvt/wprep are independent payloads that overlap the edge scan.
__global__ __launch_bounds__(512) void k_minh(
    const int* __restrict__ ei, const float* __restrict__ x,
    const float* __restrict__ Wl, const float* __restrict__ Wr,
    int* __restrict__ bmin, int* __restrict__ hist, unsigned* __restrict__ xb,
    unsigned* __restrict__ wlh, unsigned* __restrict__ wrh) {
    __shared__ int red[512];
    __shared__ int lh[NBKT];
    const int b = blockIdx.x, t = threadIdx.x;
    if (t < NBKT) lh[t] = 0;
    __syncthreads();
    int e0 = b * PER_BLK, e1 = min(e0 + PER_BLK, N_EDGES);
    int v = INT_MAX;
    for (int j = e0 + t; j < e1; j += 512) {
        int s = ei[j], d = ei[N_EDGES + j];
        v = min(v, min(s, d));
        atomicAdd(&lh[d >> 9], 1);
    }
    // x -> bf16x2 packed (grid-stride over 1.6M float4 groups)
    for (int i = b * 512 + t; i < N_NODES * HID / 4; i += BIN_NB * 512) {
        float4 xv = *(const float4*)(x + (size_t)i * 4);
        uint2 o;
        o.x = f2bf(xv.x) | (f2bf(xv.y) << 16);
        o.y = f2bf(xv.z) | (f2bf(xv.w) << 16);
        *(uint2*)(xb + (size_t)i * 2) = o;
    }
    if (b >= 250) {  // W prep: Wt[n][k] bf16; one matrix per block
        int w = b - 250;
        const float* src = (w < 3) ? (Wl + (size_t)w * HID * HID)
                                   : (Wr + (size_t)(w - 3) * HID * HID);
        unsigned* dh = (w < 3) ? (wlh + (size_t)w * HID * 64) : (wrh + (size_t)(w - 3) * HID * 64);
        for (int i = 0; i < 16; ++i) {
            int u = t * 16 + i;           // n = u>>6 (out col), kk = u&63 (k pair)
            int n = u >> 6, kk = u & 63;
            float v0 = src[(size_t)(2 * kk) * HID + n];
            float v1 = src[(size_t)(2 * kk + 1) * HID + n];
            dh[u] = f2bf(v0) | (f2bf(v1) << 16);
        }
    }
    red[t] = v;
    __syncthreads();
    for (int off = 256; off > 0; off >>= 1) {
        if (t < off) red[t] = min(red[t], red[t + off]);
        __syncthreads();
    }
    if (t == 0) bmin[b] = red[0];
    if (t < NBKT) hist[b * NBKT + t] = lh[t];
}

// ---- column scan over edge-slices -> colex, btot; + zero pooled; block0: emin + counts ----
__global__ void k_base(const int* __restrict__ hist, int* __restrict__ colex,
                       int* __restrict__ btot, float* __restrict__ pooled,
                       const int* __restrict__ bmin, int* __restrict__ emin,
                       const int* __restrict__ batch, float* __restrict__ counts) {
    __shared__ int s[BIN_NB];
    __shared__ int s2[BIN_NB];
    const int b = blockIdx.x, t = threadIdx.x;  // 98 blocks x 256 threads
    int gid = b * BIN_NB + t;                   // 25088 threads cover 24576 pooled elems
    if (gid < N_GRAPHS * HID * N_LAYER) pooled[gid] = 0.f;
    int v = hist[t * NBKT + b];
    s[t] = v;
    __syncthreads();
    for (int off = 1; off < BIN_NB; off <<= 1) {
        int u = (t >= off) ? s[t - off] : 0;
        __syncthreads();
        s[t] += u;
        __syncthreads();
    }
    colex[t * NBKT + b] = s[t] - v;
    if (t == BIN_NB - 1) btot[b] = s[t];
    if (b == 0) {  // extras: emin reduce over 256 block-mins; per-graph counts
        s2[t] = bmin[t];
        __syncthreads();
        for (int off = 128; off > 0; off >>= 1) {
            if (t < off) s2[t] = min(s2[t], s2[t + off]);
            __syncthreads();
        }
        if (t == 0) *emin = s2[0];
        if (t < N_GRAPHS) {
            int g = t;
            int lo = 0, hi = N_NODES;
            while (lo < hi) { int mid = (lo + hi) >> 1; if (batch[mid] < g) lo = mid + 1; else hi = mid; }
            int lb = lo;
            lo = lb; hi = N_NODES;
            while (lo < hi) { int mid = (lo + hi) >> 1; if (batch[mid] <= g) lo = mid + 1; else hi = mid; }
            counts[g] = (float)(lo - lb);
        }
    }
}

// ---- single-pass binning: edge -> bucket-contiguous packed ebuf (bboff scanned locally) ----
__global__ __launch_bounds__(512) void k_bin(const int* __restrict__ ei,
                                             const int* __restrict__ emin,
                                             const int* __restrict__ btot,
                                             const int* __restrict__ colex,
                                             unsigned* __restrict__ ebuf) {
    __shared__ int sb[128];
    __shared__ int lcnt[NBKT];
    __shared__ int lbase[NBKT];
    const int t = threadIdx.x, blk = blockIdx.x;
    int v = (t < NBKT) ? btot[t] : 0;
    if (t < 128) sb[t] = v;
    __syncthreads();
    for (int off = 1; off < 128; off <<= 1) {
        int u = (t >= off && t < 128) ? sb[t - off] : 0;
        __syncthreads();
        if (t < 128) sb[t] += u;
        __syncthreads();
    }
    if (t < NBKT) {
        lcnt[t] = 0;
        lbase[t] = (sb[t] - v) + colex[blk * NBKT + t];  // bboff[t] + colex
    }
    __syncthreads();
    int m = *emin;
    int e0 = blk * PER_BLK, e1 = min(e0 + PER_BLK, N_EDGES);
    for (int j = e0 + t; j < e1; j += 512) {
        int s = ei[j] - m, d = ei[N_EDGES + j];
        int bk = d >> 9;
        int idx = atomicAdd(&lcnt[bk], 1);
        ebuf[lbase[bk] + idx] = ((unsigned)s << 9) | (unsigned)(d & 511);
    }
}

// ---- per-bucket: local deg/scan -> rp, invd, then CSR placement (bboff scanned locally) ----
__global__ __launch_bounds__(512) void k_scatter2(const unsigned* __restrict__ ebuf,
                                                  const int* __restrict__ btot,
                                                  const int* __restrict__ emin,
                                                  int* __restrict__ rp,
                                                  float* __restrict__ invd,
                                                  int* __restrict__ csr) {
    __shared__ int ldeg[512];
    __shared__ int lsc[512];
    __shared__ int lfill[512];
    __shared__ int bbsh[NBKT + 1];
    const int b = blockIdx.x, t = threadIdx.x;
    // local exclusive scan of btot -> bbsh[0..98]
    int v = (t < NBKT) ? btot[t] : 0;
    if (t < 128) ldeg[t] = v;
    __syncthreads();
    for (int off = 1; off < 128; off <<= 1) {
        int u = (t >= off && t < 128) ? ldeg[t - off] : 0;
        __syncthreads();
        if (t < 128) ldeg[t] += u;
        __syncthreads();
    }
    if (t < NBKT) bbsh[t] = ldeg[t] - v;
    if (t == 127) bbsh[NBKT] = ldeg[127];
    __syncthreads();
    int m = *emin;
    if (b == NBKT) {  // tail: nodes past bucket coverage + rp[N_NODES]
        if (t == 0) rp[N_NODES] = bbsh[NBKT];
        for (int nd = NBKT * 512 - m + t; nd < N_NODES; nd += 512)
            if (nd >= 0) { rp[nd] = N_EDGES; invd[nd] = 1.0f; }
        return;
    }
    int beg = bbsh[b], end = bbsh[b + 1];
    ldeg[t] = 0;
    lfill[t] = 0;
    __syncthreads();
    for (int e = beg + t; e < end; e += 512)
        atomicAdd(&ldeg[ebuf[e] & 511], 1);
    __syncthreads();
    int dv = ldeg[t];
    lsc[t] = dv;
    __syncthreads();
    for (int off = 1; off < 512; off <<= 1) {
        int u = (t >= off) ? lsc[t - off] : 0;
        __syncthreads();
        lsc[t] += u;
        __syncthreads();
    }
    int base = beg + lsc[t] - dv;  // global CSR start for this node slot
    lsc[t] = base;
    int nd = (b << 9) + t - m;
    if (nd >= 0 && nd < N_NODES) {
        rp[nd] = base;
        invd[nd] = 1.0f / (float)max(dv, 1);
    }
    __syncthreads();
    for (int e = beg + t; e < end; e += 512) {
        unsigned p = ebuf[e];
        int loc = p & 511;
        int pos = lsc[loc] + atomicAdd(&lfill[loc], 1);
        csr[pos] = (int)(p >> 9);
    }
}

// ---------------- mean aggregation: one wave per node, full 256B rows, 16-deep MLP ----------
__global__ void k_agg(const unsigned* __restrict__ hb, const int* __restrict__ rp,
                      const int* __restrict__ csr, const float* __restrict__ invd,
                      unsigned* __restrict__ aggb) {
    const int n = blockIdx.x;
    const int lane = threadIdx.x;  // 64; lane covers features 2*lane, 2*lane+1
    int beg = rp[n], end = rp[n + 1];
    float a0 = 0, a1 = 0, b0 = 0, b1 = 0, c0 = 0, c1 = 0, d0 = 0, d1 = 0;
    int e = beg;
    for (; e + 16 <= end; e += 16) {  // 16 outstanding loads: one batch covers avg degree
        int s[16];
        unsigned u[16];
#pragma unroll
        for (int i = 0; i < 16; ++i) s[i] = csr[e + i];
#pragma unroll
        for (int i = 0; i < 16; ++i) u[i] = hb[(size_t)s[i] * 64 + lane];
#pragma unroll
        for (int i = 0; i < 16; i += 4) {
            a0 += __uint_as_float(u[i] << 16);     a1 += __uint_as_float(u[i] & 0xFFFF0000u);
            b0 += __uint_as_float(u[i + 1] << 16); b1 += __uint_as_float(u[i + 1] & 0xFFFF0000u);
            c0 += __uint_as_float(u[i + 2] << 16); c1 += __uint_as_float(u[i + 2] & 0xFFFF0000u);
            d0 += __uint_as_float(u[i + 3] << 16); d1 += __uint_as_float(u[i + 3] & 0xFFFF0000u);
        }
    }
    for (; e + 4 <= end; e += 4) {
        int s0 = csr[e], s1 = csr[e + 1], s2 = csr[e + 2], s3 = csr[e + 3];
        unsigned u0 = hb[(size_t)s0 * 64 + lane];
        unsigned u1 = hb[(size_t)s1 * 64 + lane];
        unsigned u2 = hb[(size_t)s2 * 64 + lane];
        unsigned u3 = hb[(size_t)s3 * 64 + lane];
        a0 += __uint_as_float(u0 << 16); a1 += __uint_as_float(u0 & 0xFFFF0000u);
        b0 += __uint_as_float(u1 << 16); b1 += __uint_as_float(u1 & 0xFFFF0000u);
        c0 += __uint_as_float(u2 << 16); c1 += __uint_as_float(u2 & 0xFFFF0000u);
        d0 += __uint_as_float(u3 << 16); d1 += __uint_as_float(u3 & 0xFFFF0000u);
    }
    for (; e < end; ++e) {
        unsigned u = hb[(size_t)csr[e] * 64 + lane];
        a0 += __uint_as_float(u << 16);
        a1 += __uint_as_float(u & 0xFFFF0000u);
    }
    float iv = invd[n];
    unsigned o = f2bf((a0 + b0 + c0 + d0) * iv) | (f2bf((a1 + b1 + c1 + d1) * iv) << 16);
    aggb[(size_t)n * 64 + lane] = o;
}

// ---------------- MFMA fused: h_out = relu(agg@Wl + hin@Wr + b); pooled += per-graph sums ----
// kc-loop software-pipelined: next-kc A/H fragments prefetched under current-kc MFMAs.
__global__ __launch_bounds__(256, 4) void k_gemm(
    const unsigned* __restrict__ aggb, const unsigned* __restrict__ hinb,
    const unsigned* __restrict__ wlh, const unsigned* __restrict__ wrh,
    const float* __restrict__ bias, const int* __restrict__ batch,
    unsigned* __restrict__ houtb, float* __restrict__ pooled, int layer, int store_h) {
    __shared__ float Ts[64 * 132];  // stride 132: epilogue writes <=2-way bank aliased
    __shared__ int bs[64];
    const int tx = threadIdx.x;
    const int wave = tx >> 6, lane = tx & 63;
    const int row0 = blockIdx.x * 64;
    const int lrow = lane & 15, kgrp = lane >> 4;

    if (tx < 64) {
        int grow = row0 + tx;
        bs[tx] = (grow < N_NODES) ? batch[grow] : -1;
    }

    f32x4 acc[4][2];
#pragma unroll
    for (int m = 0; m < 4; ++m)
#pragma unroll
        for (int n = 0; n < 2; ++n) acc[m][n] = (f32x4){0.f, 0.f, 0.f, 0.f};
    const short8 zf = {0, 0, 0, 0, 0, 0, 0, 0};

    short8 af[4], hf[4], afn[4], hfn[4];
    const int koff0 = kgrp * 4;
#pragma unroll
    for (int m = 0; m < 4; ++m) {  // prologue: load kc=0 fragments
        int r = row0 + m * 16 + lrow;
        if (r < N_NODES) {
            af[m] = *(const short8*)(aggb + (size_t)r * 64 + koff0);
            hf[m] = *(const short8*)(hinb + (size_t)r * 64 + koff0);
        } else {
            af[m] = zf;
            hf[m] = zf;
        }
    }
#pragma unroll
    for (int kc = 0; kc < 4; ++kc) {
        if (kc < 3) {  // prefetch kc+1 fragments; latency hides under this kc's MFMAs
            const int koffn = (kc + 1) * 16 + kgrp * 4;
#pragma unroll
            for (int m = 0; m < 4; ++m) {
                int r = row0 + m * 16 + lrow;
                if (r < N_NODES) {
                    afn[m] = *(const short8*)(aggb + (size_t)r * 64 + koffn);
                    hfn[m] = *(const short8*)(hinb + (size_t)r * 64 + koffn);
                } else {
                    afn[m] = zf;
                    hfn[m] = zf;
                }
            }
        }
        const int koff = kc * 16 + kgrp * 4;
#pragma unroll
        for (int n = 0; n < 2; ++n) {
            int wn = wave * 2 + n;  // col tile 0..7
            size_t wbase = (size_t)(wn * 16 + lrow) * 64 + koff;
            short8 fl = *(const short8*)(wlh + wbase);
            short8 fr = *(const short8*)(wrh + wbase);
#pragma unroll
            for (int m = 0; m < 4; ++m) {
                acc[m][n] = __builtin_amdgcn_mfma_f32_16x16x32_bf16(af[m], fl, acc[m][n], 0, 0, 0);
                acc[m][n] = __builtin_amdgcn_mfma_f32_16x16x32_bf16(hf[m], fr, acc[m][n], 0, 0, 0);
            }
        }
        if (kc < 3) {
#pragma unroll
            for (int m = 0; m < 4; ++m) { af[m] = afn[m]; hf[m] = hfn[m]; }
        }
    }

    // C/D layout: col = lane&15, row = (lane>>4)*4 + reg  [guide §3, m89-verified]
#pragma unroll
    for (int n = 0; n < 2; ++n) {
        int c = wave * 32 + n * 16 + lrow;
        float bb = bias[c];
#pragma unroll
        for (int m = 0; m < 4; ++m)
#pragma unroll
            for (int reg = 0; reg < 4; ++reg) {
                int r = m * 16 + kgrp * 4 + reg;
                Ts[r * 132 + c] = fmaxf(acc[m][n][reg] + bb, 0.f);
            }
    }
    __syncthreads();

    // bf16 h_out store (skipped for the last layer - no consumer)
    if (store_h) {
#pragma unroll
        for (int it = 0; it < 4; ++it) {
            int f = it * 256 + tx;
            int r = f >> 4, slot = f & 15;
            int grow = row0 + r;
            if (grow < N_NODES) {
                const float* ts = &Ts[r * 132 + slot * 8];
                uint4 o;
                o.x = f2bf(ts[0]) | (f2bf(ts[1]) << 16);
                o.y = f2bf(ts[2]) | (f2bf(ts[3]) << 16);
                o.z = f2bf(ts[4]) | (f2bf(ts[5]) << 16);
                o.w = f2bf(ts[6]) | (f2bf(ts[7]) << 16);
                *(uint4*)(houtb + (size_t)grow * 64 + slot * 4) = o;
            }
        }
    }

    // per-graph pooled pre-reduction: 256 threads = 128 cols x 2 row-halves (batch sorted)
    {
        int j = tx & 127, half = tx >> 7;
        int rbeg = half * 32, rend = rbeg + 32;
        float run = 0.f;
        int curb = bs[rbeg];
        for (int r = rbeg; r < rend; ++r) {
            int bb = bs[r];
            if (bb != curb) {
                if (curb >= 0)
                    atomicAdd(&pooled[(size_t)curb * (HID * N_LAYER) + layer * HID + j], run);
                run = 0.f;
                curb = bb;
            }
            run += Ts[r * 132 + j];
        }
        if (curb >= 0)
            atomicAdd(&pooled[(size_t)curb * (HID * N_LAYER) + layer * HID + j], run);
    }
}

// ---------------- FC head: one block per graph ----------------
__global__ void k_fc(const float* __restrict__ pooled, const float* __restrict__ counts,
                     const float* __restrict__ fc1w, const float* __restrict__ fc1b,
                     const float* __restrict__ fc2w, const float* __restrict__ fc2b,
                     float* __restrict__ out) {
    __shared__ float pr[HID * N_LAYER];
    __shared__ float a1[FC_HID];
    const int g = blockIdx.x, t = threadIdx.x;  // 256 threads
    float invc = 1.0f / fmaxf(counts[g], 1.0f);
    for (int i = t; i < HID * N_LAYER; i += FC_HID)
        pr[i] = pooled[(size_t)g * (HID * N_LAYER) + i] * invc;
    __syncthreads();
    float acc = fc1b[t];
    for (int k = 0; k < HID * N_LAYER; ++k)
        acc = fmaf(pr[k], fc1w[(size_t)k * FC_HID + t], acc);
    a1[t] = fmaxf(acc, 0.f);
    __syncthreads();
    if (t < N_CLASS) {
        float o = fc2b[t];
        for (int k = 0; k < FC_HID; ++k)
            o = fmaf(a1[k], fc2w[(size_t)k * N_CLASS + t], o);
        out[(size_t)g * N_CLASS + t] = o;
    }
}

extern "C" void kernel_launch(void* const* d_in, const int* in_sizes, int n_in,
                              void* d_out, int out_size, void* d_ws, size_t ws_size,
                              hipStream_t stream) {
    const float* x = (const float*)d_in[0];
    const int* ei = (const int*)d_in[1];
    const int* batch = (const int*)d_in[2];
    const float* Wl = (const float*)d_in[3];
    const float* Wr = (const float*)d_in[4];
    const float* bl = (const float*)d_in[5];
    const float* fc1w = (const float*)d_in[6];
    const float* fc1b = (const float*)d_in[7];
    const float* fc2w = (const float*)d_in[8];
    const float* fc2b = (const float*)d_in[9];
    float* out = (float*)d_out;

    char* ws = (char*)d_ws;
    size_t off = 0;
    auto alloc = [&](size_t bytes) {
        void* p = ws + off;
        off += (bytes + 255) & ~size_t(255);
        return p;
    };
    // all buffers fully written on-device every call -> no memsets needed
    int* emin = (int*)alloc(4);
    int* bmin = (int*)alloc(BIN_NB * 4);
    float* pooled = (float*)alloc((size_t)N_GRAPHS * HID * N_LAYER * 4);  // zeroed by k_base
    int* hist = (int*)alloc((size_t)BIN_NB * NBKT * 4);
    int* colex = (int*)alloc((size_t)BIN_NB * NBKT * 4);
    int* btot = (int*)alloc(NBKT * 4);
    int* rp = (int*)alloc((N_NODES + 1) * 4);
    float* invd = (float*)alloc(N_NODES * 4);
    float* counts = (float*)alloc(N_GRAPHS * 4);
    unsigned* ebuf = (unsigned*)alloc((size_t)N_EDGES * 4);
    int* csr = (int*)alloc((size_t)N_EDGES * 4);
    unsigned* wlh = (unsigned*)alloc((size_t)N_LAYER * HID * 64 * 4);
    unsigned* wrh = (unsigned*)alloc((size_t)N_LAYER * HID * 64 * 4);
    unsigned* aggb = (unsigned*)alloc((size_t)N_NODES * 64 * 4);   // bf16x2 packed
    unsigned* xb = (unsigned*)alloc((size_t)N_NODES * 64 * 4);
    unsigned* hb1 = (unsigned*)alloc((size_t)N_NODES * 64 * 4);
    unsigned* hb2 = (unsigned*)alloc((size_t)N_NODES * 64 * 4);

    k_minh<<<BIN_NB, 512, 0, stream>>>(ei, x, Wl, Wr, bmin, hist, xb, wlh, wrh);
    k_base<<<NBKT, BIN_NB, 0, stream>>>(hist, colex, btot, pooled, bmin, emin, batch, counts);
    k_bin<<<BIN_NB, 512, 0, stream>>>(ei, emin, btot, colex, ebuf);
    k_scatter2<<<NBKT + 1, 512, 0, stream>>>(ebuf, btot, emin, rp, invd, csr);

    const unsigned* hin = xb;
    unsigned* houts[3] = {hb1, hb2, hb1};
    for (int layer = 0; layer < N_LAYER; ++layer) {
        k_agg<<<N_NODES, 64, 0, stream>>>(hin, rp, csr, invd, aggb);
        k_gemm<<<(N_NODES + 63) / 64, 256, 0, stream>>>(
            aggb, hin,
            wlh + (size_t)layer * HID * 64, wrh + (size_t)layer * HID * 64,
            bl + (size_t)layer * HID, batch, houts[layer], pooled, layer,
            layer < N_LAYER - 1 ? 1 : 0);
        hin = houts[layer];
    }
    k_fc<<<N_GRAPHS, 256, 0, stream>>>(pooled, counts, fc1w, fc1b, fc2w, fc2b, out);
}